// Round 14
// baseline (370.718 us; speedup 1.0000x reference)
//
#include <hip/hip_runtime.h>
#include <hip/hip_bf16.h>
#include <math.h>

#define N_PTS 16384
#define NLAYER 4

typedef __attribute__((ext_vector_type(8))) short bfrag;
typedef __attribute__((ext_vector_type(4))) float f32x4;
typedef unsigned short ushort_t;
typedef unsigned int uint_t;

__device__ __forceinline__ ushort_t f2b(float f) {
  __hip_bfloat16 h = __float2bfloat16(f);
  return *reinterpret_cast<const ushort_t*>(&h);
}
__device__ __forceinline__ float b2f(ushort_t u) {
  union { uint_t i; float f; } c; c.i = ((uint_t)u) << 16; return c.f;
}
__device__ __forceinline__ float blo(uint_t u) {
  union { uint_t i; float f; } c; c.i = u << 16; return c.f;
}
__device__ __forceinline__ float bhi(uint_t u) {
  union { uint_t i; float f; } c; c.i = u & 0xffff0000u; return c.f;
}

#define MFMA16(a, b, c) __builtin_amdgcn_mfma_f32_16x16x32_bf16((a), (b), (c), 0, 0, 0)

// ---------------------------------------------------------------------------
__global__ __launch_bounds__(256) void base_kernel(
    const float* __restrict__ enc, const float* __restrict__ W_in,
    const float* __restrict__ b_in, float* __restrict__ base)
{
  int b = blockIdx.x, j = threadIdx.x;
  __shared__ float se[256];
  se[j] = enc[b * 256 + j];
  __syncthreads();
  float acc = b_in[j] + W_in[j];
  for (int i = 1; i < 256; ++i) acc += se[i] * W_in[i * 256 + j];
  base[b * 256 + j] = acc;
}

// h row-major bf16 + fragment-order hbP
__global__ __launch_bounds__(256) void embed_kernel(
    const float* __restrict__ base, const int* __restrict__ batch_idx,
    const float* __restrict__ pos, const float* __restrict__ W_in,
    ushort_t* __restrict__ h_bf, ushort_t* __restrict__ hbP)
{
  int n = blockIdx.x, j = threadIdx.x;
  int b = batch_idx[n];
  float px = pos[n * 3 + 0], py = pos[n * 3 + 1], pz = pos[n * 3 + 2];
  float v = base[b * 256 + j]
      + px * W_in[256 * 256 + j] + py * W_in[257 * 256 + j] + pz * W_in[258 * 256 + j];
  ushort_t u = f2b(v);
  h_bf[(size_t)n * 256 + j] = u;
  int rt = n >> 4, ct = j >> 4;
  int lane = ((n & 15) >> 2) * 16 + (j & 15);
  hbP[(((size_t)rt * 16 + ct) * 64 + lane) * 4 + (n & 3)] = u;
}

// ---------------------------------------------------------------------------
// W3P (qkv): [ct 0..39][ks 0..7] per-(ct,ks) 1KB fragment blocks.
__global__ __launch_bounds__(256) void prep_qkv(
    const float* __restrict__ Wq, const float* __restrict__ Wk,
    const float* __restrict__ Wv, const float* __restrict__ We,
    ushort_t* __restrict__ out)
{
  int idx = blockIdx.x * 256 + threadIdx.x;  // < 4*640*256
  int l = idx / (640 * 256);
  int rem = idx - l * (640 * 256);
  int c = rem >> 8, k = rem & 255;
  float v = 0.f;
  if (c < 128) v = Wq[((size_t)l * 256 + k) * 128 + c];
  else if (c < 328) {
    int p = c - 128, hq = p / 50, r = p - hq * 50;
    const float* wq = &Wq[((size_t)l * 256 + k) * 128 + hq * 32];
    const float* we = &We[((size_t)l * 50 + r) * 128 + hq * 32];
#pragma unroll
    for (int d = 0; d < 32; ++d) v += wq[d] * we[d];
  } else if (c < 456) v = Wk[((size_t)l * 256 + k) * 128 + (c - 328)];
  else if (c < 584) v = Wv[((size_t)l * 256 + k) * 128 + (c - 456)];
  size_t pos = (size_t)l * 163840
      + (((c >> 4) * 8 + (k >> 5)) * 64 + ((k >> 3) & 3) * 16 + (c & 15)) * 8 + (k & 7);
  out[pos] = f2b(v);
}

// BcP: [ks 0..10][ct 0..15] fragment blocks (K=352 packed).
__global__ __launch_bounds__(256) void prep_bcat(
    const float* __restrict__ We, const float* __restrict__ Wo, ushort_t* __restrict__ out)
{
  int idx = blockIdx.x * 256 + threadIdx.x;  // < 4*256*352
  if (idx >= 4 * 256 * 352) return;
  int l = idx / (256 * 352);
  int rem = idx - l * (256 * 352);
  int c = rem / 352, k = rem - c * 352;
  float v = 0.f;
  if (k < 128) v = Wo[((size_t)l * 128 + k) * 256 + c];
  else if (k < 328) {
    int p = k - 128, hq = p / 50, r = p - hq * 50;
    const float* we = &We[((size_t)l * 50 + r) * 128 + hq * 32];
    const float* wo = &Wo[((size_t)l * 128 + hq * 32) * 256 + c];
#pragma unroll
    for (int d = 0; d < 32; ++d) v += we[d] * wo[(size_t)d * 256];
  }
  size_t pos = (size_t)l * 90112
      + (((k >> 5) * 16 + (c >> 4)) * 64 + ((k >> 3) & 3) * 16 + (c & 15)) * 8 + (k & 7);
  out[pos] = f2b(v);
}

// WfP: [ks 0..7][ct 0..15]
__global__ __launch_bounds__(256) void prep_wfc(
    const float* __restrict__ Wfc, ushort_t* __restrict__ out)
{
  int idx = blockIdx.x * 256 + threadIdx.x;  // < 4*256*256
  int l = idx >> 16, rem = idx & 65535;
  int c = rem >> 8, k = rem & 255;
  float v = Wfc[((size_t)l * 256 + k) * 256 + c];
  size_t pos = (size_t)l * 65536
      + (((k >> 5) * 16 + (c >> 4)) * 64 + ((k >> 3) & 3) * 16 + (c & 15)) * 8 + (k & 7);
  out[pos] = f2b(v);
}

// WoP: [ct 0..7][ks 0..7] (cols padded to 128)
__global__ __launch_bounds__(256) void prep_wout(
    const float* __restrict__ W_out, ushort_t* __restrict__ out)
{
  int idx = blockIdx.x * 256 + threadIdx.x;  // < 128*256
  int c = idx >> 8, k = idx & 255;
  float v = (c < 103) ? W_out[(size_t)k * 103 + c] : 0.f;
  size_t pos = (((c >> 4) * 8 + (k >> 5)) * 64 + ((k >> 3) & 3) * 16 + (c & 15)) * 8 + (k & 7);
  out[pos] = f2b(v);
}

// ---------------------------------------------------------------------------
// Wave-autonomous fused layer: 1024 blocks x 128 thr (2 waves). Block owns 16
// rows; wave owns a column half. No barriers in GEMM loops; B-frags stream
// from fragment-packed weights (fully coalesced). 4 tiny 2-wave barriers.
// MODE 0: full layer -> qkv. MODE 1: full layer -> out. MODE 2: qkv only.
template<int MODE>
__global__ __launch_bounds__(128) void fused_layer(
    const ushort_t* __restrict__ Amsg,  // [N][352] (MODE!=2)
    const ushort_t* __restrict__ BcP,   // packed [11][16] 1KB blocks
    const float* __restrict__ bo,
    ushort_t* __restrict__ hbP,         // fragment-order residual stream
    const float* __restrict__ lg, const float* __restrict__ lb,
    const ushort_t* __restrict__ WfP,   // packed [8][16]
    const float* __restrict__ bfc,
    const ushort_t* __restrict__ W3P,   // packed [40][8] (qkv) or [8][8] (out)
    const float* __restrict__ b3,
    const ushort_t* __restrict__ h_bf,  // row-major h (MODE 2)
    ushort_t* __restrict__ qext_b, ushort_t* __restrict__ kvb,
    float* __restrict__ outF)
{
  __shared__ __align__(16) ushort_t tb[16 * 264];   // 8.4 KB transpose buffer
  __shared__ float pS[2][16], pSS[2][16];

  const int tid = threadIdx.x;
  const int lane = tid & 63, wv = tid >> 6;
  const int l15 = lane & 15, l4 = lane >> 4;
  const int rt = blockIdx.x;
  const int r0 = rt * 16;

  if constexpr (MODE != 2) {
    const int cb = wv * 8;   // ct base for this wave (G1/G2)

    // ---- G1 A-frags: 11 gathers into registers (one-time)
    bfrag aA[11];
#pragma unroll
    for (int ks = 0; ks < 11; ++ks)
      aA[ks] = *(const bfrag*)(Amsg + (size_t)(r0 + l15) * 352 + ks * 32 + l4 * 8);

    // ---- GEMM1: acc[8 ct] over K=352, B streamed from BcP
    f32x4 acc[8];
#pragma unroll
    for (int j = 0; j < 8; ++j) acc[j] = (f32x4){0.f, 0.f, 0.f, 0.f};
#pragma unroll
    for (int ks = 0; ks < 11; ++ks) {
#pragma unroll
      for (int j = 0; j < 8; ++j) {
        bfrag b = *(const bfrag*)(BcP + (((size_t)ks * 16 + cb + j) * 64 + lane) * 8);
        acc[j] = MFMA16(aA[ks], b, acc[j]);
      }
    }

    // ---- epilogue 1: + bo + resid(hbP), LN stats (wave-local + 1 exchange)
    float s0 = 0.f, s1 = 0.f, s2 = 0.f, s3 = 0.f;
    float q0 = 0.f, q1 = 0.f, q2 = 0.f, q3 = 0.f;
#pragma unroll
    for (int j = 0; j < 8; ++j) {
      const int c = (cb + j) * 16 + l15;
      const float boc = bo[c];
      uint2 hv = *(const uint2*)(hbP + (((size_t)rt * 16 + cb + j) * 64 + lane) * 4);
      const ushort_t* hu = (const ushort_t*)&hv;
      float x0 = acc[j][0] + boc + b2f(hu[0]);
      float x1 = acc[j][1] + boc + b2f(hu[1]);
      float x2 = acc[j][2] + boc + b2f(hu[2]);
      float x3 = acc[j][3] + boc + b2f(hu[3]);
      acc[j][0] = x0; acc[j][1] = x1; acc[j][2] = x2; acc[j][3] = x3;
      s0 += x0; q0 += x0 * x0; s1 += x1; q1 += x1 * x1;
      s2 += x2; q2 += x2 * x2; s3 += x3; q3 += x3 * x3;
    }
#pragma unroll
    for (int off = 1; off < 16; off <<= 1) {
      s0 += __shfl_xor(s0, off, 64); q0 += __shfl_xor(q0, off, 64);
      s1 += __shfl_xor(s1, off, 64); q1 += __shfl_xor(q1, off, 64);
      s2 += __shfl_xor(s2, off, 64); q2 += __shfl_xor(q2, off, 64);
      s3 += __shfl_xor(s3, off, 64); q3 += __shfl_xor(q3, off, 64);
    }
    if (l15 == 0) {
      pS[wv][l4 * 4 + 0] = s0; pSS[wv][l4 * 4 + 0] = q0;
      pS[wv][l4 * 4 + 1] = s1; pSS[wv][l4 * 4 + 1] = q1;
      pS[wv][l4 * 4 + 2] = s2; pSS[wv][l4 * 4 + 2] = q2;
      pS[wv][l4 * 4 + 3] = s3; pSS[wv][l4 * 4 + 3] = q3;
    }
    __syncthreads();
    float mu[4], inv[4];
#pragma unroll
    for (int i = 0; i < 4; ++i) {
      const int r = l4 * 4 + i;
      float S = pS[0][r] + pS[1][r];
      float Q = pSS[0][r] + pSS[1][r];
      float m = S * (1.f / 256.f);
      float var = Q * (1.f / 256.f) - m * m;
      mu[i] = m;
      inv[i] = 1.0f / sqrtf(var + 1e-5f);
    }
    // LN -> tb[row][col]
#pragma unroll
    for (int j = 0; j < 8; ++j) {
      const int c = (cb + j) * 16 + l15;
      const float g = lg[c], bb = lb[c];
#pragma unroll
      for (int i = 0; i < 4; ++i)
        tb[(l4 * 4 + i) * 264 + c] = f2b(g * (acc[j][i] - mu[i]) * inv[i] + bb);
    }
    __syncthreads();

    // ---- G2 A-frags from tb (full K=256)
    bfrag aH[8];
#pragma unroll
    for (int ks = 0; ks < 8; ++ks)
      aH[ks] = *(const bfrag*)(tb + l15 * 264 + ks * 32 + l4 * 8);
    __syncthreads();   // both waves done reading tb -> safe to overwrite later

    // ---- GEMM2: acc[8 ct] over K=256, B from WfP
#pragma unroll
    for (int j = 0; j < 8; ++j) acc[j] = (f32x4){0.f, 0.f, 0.f, 0.f};
#pragma unroll
    for (int ks = 0; ks < 8; ++ks) {
#pragma unroll
      for (int j = 0; j < 8; ++j) {
        bfrag b = *(const bfrag*)(WfP + (((size_t)ks * 16 + cb + j) * 64 + lane) * 8);
        acc[j] = MFMA16(aH[ks], b, acc[j]);
      }
    }

    // ---- epilogue 2: gelu -> hbP (coalesced) + tb
#pragma unroll
    for (int j = 0; j < 8; ++j) {
      const int c = (cb + j) * 16 + l15;
      const float bfcc = bfc[c];
      ushort_t uo[4];
#pragma unroll
      for (int i = 0; i < 4; ++i) {
        float x = acc[j][i] + bfcc;
        float t = tanhf(0.7978845608028654f * (x + 0.044715f * x * x * x));
        float gl = 0.5f * x * (1.f + t);
        uo[i] = f2b(gl);
        tb[(l4 * 4 + i) * 264 + c] = uo[i];
      }
      *(uint2*)(hbP + (((size_t)rt * 16 + cb + j) * 64 + lane) * 4) = *(const uint2*)uo;
    }
    __syncthreads();
  }

  // ---- G3 A-frags
  bfrag aG[8];
  if constexpr (MODE == 2) {
#pragma unroll
    for (int ks = 0; ks < 8; ++ks)
      aG[ks] = *(const bfrag*)(h_bf + (size_t)(r0 + l15) * 256 + ks * 32 + l4 * 8);
  } else {
#pragma unroll
    for (int ks = 0; ks < 8; ++ks)
      aG[ks] = *(const bfrag*)(tb + l15 * 264 + ks * 32 + l4 * 8);
  }

  // ---- GEMM3: wave owns NCT col-tiles, chunks of 4, B from W3P [ct][ks]
  const int NCT = (MODE == 1) ? 4 : 20;
  const int cg = wv * NCT;
  for (int ch = 0; ch < NCT; ch += 4) {
    f32x4 a3[4];
#pragma unroll
    for (int j = 0; j < 4; ++j) a3[j] = (f32x4){0.f, 0.f, 0.f, 0.f};
#pragma unroll
    for (int ks = 0; ks < 8; ++ks) {
#pragma unroll
      for (int j = 0; j < 4; ++j) {
        const int ct = cg + ch + j;
        bfrag b = *(const bfrag*)(W3P + (((size_t)ct * 8 + ks) * 64 + lane) * 8);
        a3[j] = MFMA16(aG[ks], b, a3[j]);
      }
    }
#pragma unroll
    for (int j = 0; j < 4; ++j) {
      const int c = (cg + ch + j) * 16 + l15;
#pragma unroll
      for (int i = 0; i < 4; ++i) {
        const size_t r = (size_t)(r0 + l4 * 4 + i);
        float v = a3[j][i];
        if constexpr (MODE == 1) {
          if (c < 103) outF[r * 103 + c] = v + b3[c];
        } else {
          if (c < 328) qext_b[r * 352 + c] = f2b(v);
          else if (c < 584) kvb[r * 256 + (c - 328)] = f2b(v);
        }
      }
    }
  }
}

// ---------------------------------------------------------------------------
// Attention: K/V straight from L2, all LDS per-wave, no block barriers.
__global__ __launch_bounds__(256) void attn_kernel(
    const ushort_t* __restrict__ qext, const ushort_t* __restrict__ kvb,
    const float* __restrict__ pos, const int* __restrict__ nbrs,
    const float* __restrict__ mask, ushort_t* __restrict__ Amsg)
{
  __shared__ __align__(16) ushort_t sQ[4][128];
  __shared__ __align__(16) float    sQE[4][4][52];
  __shared__ __align__(16) ushort_t sRbf[4][16][52];
  __shared__ float sA[4][64];
  __shared__ float sD[4][16];
  __shared__ float sMk[4][16];
  __shared__ int   sNb[4][16];

  const int tid = threadIdx.x;
  const int bid = blockIdx.x;
  const int lane = tid & 63, w = tid >> 6;
  const int g = (bid & 7) + 8 * ((bid >> 3) & 15);
  const int q4 = bid >> 7;
  const int kk = lane >> 2, hh = lane & 3;

  for (int it = 0; it < 4; ++it) {
    const int n = g * 128 + q4 * 16 + w * 4 + it;
    if (lane < 16) {
      int nb = nbrs[n * 16 + lane];
      sNb[w][lane] = nb;
      sMk[w][lane] = mask[n * 16 + lane];
      float dx = pos[nb * 3 + 0] - pos[n * 3 + 0];
      float dy = pos[nb * 3 + 1] - pos[n * 3 + 1];
      float dz = pos[nb * 3 + 2] - pos[n * 3 + 2];
      sD[w][lane] = sqrtf(dx * dx + dy * dy + dz * dz + 1e-12f);
      sRbf[w][lane][50] = 0; sRbf[w][lane][51] = 0;
      *(uint4*)(&sQ[w][lane * 8]) = *(const uint4*)(qext + (size_t)n * 352 + lane * 8);
    }
    if (lane < 50) {
      uint2 u = *(const uint2*)(qext + (size_t)n * 352 + 128 + lane * 4);
      int p = lane * 4;
#pragma unroll
      for (int e = 0; e < 4; ++e) {
        ushort_t bb = ((const ushort_t*)&u)[e];
        int pp = p + e, h2 = pp / 50, r = pp - h2 * 50;
        sQE[w][h2][r] = b2f(bb);
      }
    }
    if (lane < 8) sQE[w][lane >> 1][50 + (lane & 1)] = 0.f;
    {
      int kk2 = lane & 15;
      float dk = sD[w][kk2];
      int r0 = lane >> 4;
#pragma unroll
      for (int j = 0; j < 13; ++j) {
        int r = r0 + j * 4;
        if (r < 50) {
          float t = (dk - (2.f / 49.f) * (float)r) * 24.5f;
          sRbf[w][kk2][r] = f2b(__expf(-0.5f * t * t));
        }
      }
    }
    const int nb = sNb[w][kk];
    const ushort_t* krow = kvb + (size_t)nb * 256 + hh * 32;
    float qk = 0.f;
#pragma unroll
    for (int c8 = 0; c8 < 4; ++c8) {
      uint4 kv4 = *(const uint4*)(krow + c8 * 8);
      const uint_t* q4p = (const uint_t*)(&sQ[w][hh * 32 + c8 * 8]);
      uint_t qa = q4p[0], qb = q4p[1], qc = q4p[2], qd = q4p[3];
      qk += blo(qa) * blo(kv4.x) + bhi(qa) * bhi(kv4.x)
          + blo(qb) * blo(kv4.y) + bhi(qb) * bhi(kv4.y)
          + blo(qc) * blo(kv4.z) + bhi(qc) * bhi(kv4.z)
          + blo(qd) * blo(kv4.w) + bhi(qd) * bhi(kv4.w);
    }
    float qe = 0.f;
#pragma unroll
    for (int c = 0; c < 13; ++c) {
      float4 qv = *(const float4*)(&sQE[w][hh][c * 4]);
      uint2 rv = *(const uint2*)(&sRbf[w][kk][c * 4]);
      qe += qv.x * blo(rv.x) + qv.y * bhi(rv.x)
          + qv.z * blo(rv.y) + qv.w * bhi(rv.y);
    }
    float lg = 0.17677669529663687f * (qk + qe);
    lg = (sMk[w][kk] > 0.f) ? lg : -1e9f;

    float mx = lg;
#pragma unroll
    for (int off = 4; off < 64; off <<= 1) mx = fmaxf(mx, __shfl_xor(mx, off, 64));
    float ex = __expf(lg - mx);
    float sm = ex;
#pragma unroll
    for (int off = 4; off < 64; off <<= 1) sm += __shfl_xor(sm, off, 64);
    sA[w][kk * 4 + hh] = ex / sm * sMk[w][kk];

    if (lane < 50) {
      float r0 = 0.f, r1 = 0.f, r2 = 0.f, r3 = 0.f;
#pragma unroll
      for (int k2 = 0; k2 < 16; ++k2) {
        float rb = b2f(sRbf[w][k2][lane]);
        r0 += sA[w][k2 * 4 + 0] * rb;
        r1 += sA[w][k2 * 4 + 1] * rb;
        r2 += sA[w][k2 * 4 + 2] * rb;
        r3 += sA[w][k2 * 4 + 3] * rb;
      }
      Amsg[(size_t)n * 352 + 128 + 0 * 50 + lane] = f2b(r0);
      Amsg[(size_t)n * 352 + 128 + 1 * 50 + lane] = f2b(r1);
      Amsg[(size_t)n * 352 + 128 + 2 * 50 + lane] = f2b(r2);
      Amsg[(size_t)n * 352 + 128 + 3 * 50 + lane] = f2b(r3);
    }
    {
      const int h2 = lane >> 4;
      float m0v = 0.f, m1v = 0.f;
#pragma unroll
      for (int k2 = 0; k2 < 16; ++k2) {
        int nb2 = sNb[w][k2];
        uint_t vv = *(const uint_t*)(kvb + (size_t)nb2 * 256 + 128 + lane * 2);
        float a = sA[w][k2 * 4 + h2];
        m0v += a * blo(vv);
        m1v += a * bhi(vv);
      }
      uint_t o = (uint_t)f2b(m0v) | ((uint_t)f2b(m1v) << 16);
      *(uint_t*)(&Amsg[(size_t)n * 352 + lane * 2]) = o;
    }
    if (lane < 24) Amsg[(size_t)n * 352 + 328 + lane] = 0;
  }
}

// ---------------------------------------------------------------------------
extern "C" void kernel_launch(void* const* d_in, const int* in_sizes, int n_in,
                              void* d_out, int out_size, void* d_ws, size_t ws_size,
                              hipStream_t stream) {
  const float* enc    = (const float*)d_in[0];
  const float* pos    = (const float*)d_in[1];
  const int*   bidx   = (const int*)  d_in[2];
  const int*   nbrs   = (const int*)  d_in[3];
  const float* mask   = (const float*)d_in[4];
  const float* W_in   = (const float*)d_in[5];
  const float* b_in   = (const float*)d_in[6];
  const float* Wq     = (const float*)d_in[7];
  const float* Wk     = (const float*)d_in[8];
  const float* Wv     = (const float*)d_in[9];
  const float* We     = (const float*)d_in[10];
  const float* Wo     = (const float*)d_in[11];
  const float* bo     = (const float*)d_in[12];
  const float* Wfc    = (const float*)d_in[13];
  const float* bfc    = (const float*)d_in[14];
  const float* ln_g   = (const float*)d_in[15];
  const float* ln_b   = (const float*)d_in[16];
  const float* W_out  = (const float*)d_in[17];
  const float* b_out  = (const float*)d_in[18];
  float* out = (float*)d_out;

  const int N = N_PTS;
  ushort_t* ws = (ushort_t*)d_ws;
  ushort_t* hbP    = ws;                                  // N*256 frag-order
  ushort_t* h_bf   = hbP + (size_t)N * 256;               // N*256 row-major
  ushort_t* qext_b = h_bf + (size_t)N * 256;              // N*352
  ushort_t* kvb    = qext_b + (size_t)N * 352;            // N*256
  ushort_t* Amsg   = kvb + (size_t)N * 256;               // N*352
  float*    base   = (float*)(Amsg + (size_t)N * 352);    // 128*256 fp32
  ushort_t* W3P    = (ushort_t*)(base + 128 * 256);       // 4*163840
  ushort_t* BcP    = W3P + 4 * 163840;                    // 4*90112
  ushort_t* WfP    = BcP + 4 * 90112;                     // 4*65536
  ushort_t* WoP    = WfP + 4 * 65536;                     // 32768

  base_kernel<<<128, 256, 0, stream>>>(enc, W_in, b_in, base);
  embed_kernel<<<N, 256, 0, stream>>>(base, bidx, pos, W_in, h_bf, hbP);
  prep_qkv<<<(4 * 640 * 256) / 256, 256, 0, stream>>>(Wq, Wk, Wv, We, W3P);
  prep_bcat<<<(4 * 256 * 352 + 255) / 256, 256, 0, stream>>>(We, Wo, BcP);
  prep_wfc<<<(4 * 256 * 256) / 256, 256, 0, stream>>>(Wfc, WfP);
  prep_wout<<<(128 * 256) / 256, 256, 0, stream>>>(W_out, WoP);

  // layer-0 qkv from embedded features
  fused_layer<2><<<N / 16, 128, 0, stream>>>(
      nullptr, nullptr, nullptr, nullptr, nullptr, nullptr, nullptr, nullptr,
      W3P, nullptr, h_bf, qext_b, kvb, nullptr);

  for (int l = 0; l < NLAYER; ++l) {
    const ushort_t* BcP_l = BcP + (size_t)l * 90112;
    const ushort_t* WfP_l = WfP + (size_t)l * 65536;
    const float* bo_l  = bo  + (size_t)l * 256;
    const float* bfc_l = bfc + (size_t)l * 256;
    const float* lg_l  = ln_g + (size_t)l * 256;
    const float* lb_l  = ln_b + (size_t)l * 256;

    attn_kernel<<<1024, 256, 0, stream>>>(qext_b, kvb, pos, nbrs, mask, Amsg);

    if (l < NLAYER - 1) {
      const ushort_t* W3P_next = W3P + (size_t)(l + 1) * 163840;
      fused_layer<0><<<N / 16, 128, 0, stream>>>(
          Amsg, BcP_l, bo_l, hbP, lg_l, lb_l, WfP_l, bfc_l,
          W3P_next, nullptr, nullptr, qext_b, kvb, nullptr);
    } else {
      fused_layer<1><<<N / 16, 128, 0, stream>>>(
          Amsg, BcP_l, bo_l, hbP, lg_l, lb_l, WfP_l, bfc_l,
          WoP, b_out, nullptr, nullptr, nullptr, out);
    }
  }
}